// Round 11
// baseline (94.157 us; speedup 1.0000x reference)
//
#include <hip/hip_runtime.h>
#include <hip/hip_bf16.h>

typedef __attribute__((ext_vector_type(4))) int i32x4;
typedef __attribute__((ext_vector_type(8))) int i32x8;
typedef __attribute__((ext_vector_type(4))) float f32x4;
typedef __attribute__((ext_vector_type(16))) float f32x16;

#define BM 256
#define BN 128
#define THREADS 512
#define STB 24576          // stage-tile: A 256r x 64B (16KB) + B 128r x 64B (8KB)
#define SA_OFF 73728       // f32 sa[4][256]
#define SB_OFF 77824       // f32 sb[4][128]
#define LDS_TOTAL 79872    // 78 KB -> 2 blocks/CU

#define VMCNT(n) asm volatile("s_waitcnt vmcnt(" #n ")" ::: "memory")

static __device__ inline void gload_lds16(const void* g, void* l) {
  __builtin_amdgcn_global_load_lds((__attribute__((address_space(1))) void*)g,
                                   (__attribute__((address_space(3))) void*)l,
                                   16, 0, 0);
}

// ---------------- QDQ -> packed E2M1 fp4 (value q in {0,+-0.5,+-1}) + f32 scales ----
// nibble: 0->0x0, 0.5->0x1, 1.0->0x2, sign->bit3. Low nibble = lower element index.
__global__ __launch_bounds__(256) void qdq_fp4(const float* __restrict__ x,
                                               unsigned short* __restrict__ qx,
                                               float* __restrict__ sax, int gx,
                                               const float* __restrict__ w,
                                               unsigned short* __restrict__ qw,
                                               float* __restrict__ sbx, int gtot) {
  int g = (blockIdx.x << 2) + (threadIdx.x >> 6);
  if (g >= gtot) return;
  const int lane = threadIdx.x & 63;
  const bool isx = (g < gx);
  const int gl = isx ? g : g - gx;
  const float* src = isx ? x : w;
  unsigned short* dst = isx ? qx : qw;
  float* sc = isx ? sax : sbx;

  const size_t base = (size_t)gl * 256 + (size_t)lane * 4;
  float4 v = *reinterpret_cast<const float4*>(src + base);
  float amax = fmaxf(fmaxf(fabsf(v.x), fabsf(v.y)), fmaxf(fabsf(v.z), fabsf(v.w)));
#pragma unroll
  for (int off = 32; off > 0; off >>= 1)
    amax = fmaxf(amax, __shfl_xor(amax, off, 64));
  const float scale = fmaxf(amax, 1e-6f);
  float in[4] = {v.x, v.y, v.z, v.w};
  unsigned enc = 0;
#pragma unroll
  for (int i = 0; i < 4; ++i) {
    float t = fabsf(in[i] / scale);
    unsigned q = t < 0.25f ? 0u : (t < 0.75f ? 1u : 2u);   // E2M1: 0 / 0.5 / 1.0
    if (in[i] < 0.0f) q |= 8u;
    enc |= q << (4 * i);
  }
  dst[(size_t)gl * 64 + lane] = (unsigned short)enc;       // 4 nibbles = 2 bytes
  if (lane == 0) sc[gl] = scale;
}

// ---------------- GEMM fp4: 8 waves x (64x64), 3-slot ring, 2 blocks/CU --------------
// K-loop identical to r10 (verified, absmax 0.0156). NEW: coalesced epilogue --
// C tile staged through LDS (2 passes x 64KB, XOR chunk swizzle c^(rl&7) both-sides),
// stores become 2 rows x 512B contiguous f32x4 per instruction (was 128B segments).
__global__ __launch_bounds__(THREADS, 2) void gemm_fp4(
    const unsigned char* __restrict__ A4,  // [M][K/2]
    const unsigned char* __restrict__ B4,  // [N][K/2]
    const float* __restrict__ sax,         // [M*4]
    const float* __restrict__ sbx,         // [N*4]
    const float* __restrict__ bias,        // [N]
    float* __restrict__ C,                 // [M,N]
    int M, int N, int K) {
  extern __shared__ char smem[];

  const int tid = threadIdx.x;
  const int lane = tid & 63;
  const int wid = tid >> 6;      // 0..7
  const int wrow = wid >> 1;     // 0..3 -> 64-row strip of 256
  const int wcol = wid & 1;      // 0..1 -> 64-col strip of 128
  const int l31 = lane & 31;
  const int hi2 = lane >> 5;     // k-half within 64

  const int nwg = gridDim.x;
  int bid = blockIdx.x;
  if ((nwg & 7) == 0) bid = (bid & 7) * (nwg >> 3) + (bid >> 3);
  const int ntn = N / BN;
  const int tm = bid / ntn, tn = bid % ntn;
  const int m0 = tm * BM, n0 = tn * BN;

  // scales
  float* sa_lds = (float*)(smem + SA_OFF);
  float* sb_lds = (float*)(smem + SB_OFF);
#pragma unroll
  for (int p = 0; p < 2; ++p) {
    int idx = p * 512 + tid, row = idx & 255, gg = idx >> 8;
    sa_lds[gg * 256 + row] = sax[(size_t)(m0 + row) * 4 + gg];
  }
  { int row = tid & 127, gg = (tid >> 7) & 3;
    sb_lds[gg * 128 + row] = sbx[(size_t)(n0 + row) * 4 + gg]; }
  __syncthreads();

  // staging source map (inverse pair-line swizzle; verbatim r5/r7, measured 0-conflict)
  const int u = (tid & 7) ^ ((tid >> 3) & 7);
  const int rr = 2 * (tid >> 3) + (u >> 2);   // 0..127
  const int cBy = (u & 3) * 16;
  const int Kb = K >> 1;                       // bytes per row
  const size_t srcA = (size_t)(m0 + rr) * Kb + cBy;
  const size_t srcB = (size_t)(n0 + rr) * Kb + cBy;
  const size_t aRowStep = (size_t)128 * Kb;
  const int d16 = tid * 16;

#define STAGE(slot, st) do {                                          \
    char* bb = smem + (slot) * STB;                                   \
    const unsigned char* ga = A4 + srcA + (size_t)(st) * 64;          \
    gload_lds16(ga,            bb + d16);                             \
    gload_lds16(ga + aRowStep, bb + 8192 + d16);                      \
    gload_lds16(B4 + srcB + (size_t)(st) * 64, bb + 16384 + d16);     \
  } while (0)

  // fragment read addresses: frag (i|j), k-step s
  int aAddr[2][2], bAddr[2][2];
#pragma unroll
  for (int i = 0; i < 2; ++i) {
    const int r = wrow * 64 + i * 32 + l31;
#pragma unroll
    for (int s = 0; s < 2; ++s) {
      const int c16 = s * 2 + hi2;
      aAddr[i][s] = (r >> 1) * 128 + (((c16 + 4 * (r & 1)) ^ ((r >> 1) & 7)) << 4);
    }
  }
#pragma unroll
  for (int j = 0; j < 2; ++j) {
    const int r = wcol * 64 + j * 32 + l31;
#pragma unroll
    for (int s = 0; s < 2; ++s) {
      const int c16 = s * 2 + hi2;
      bAddr[j][s] = 16384 + (r >> 1) * 128 + (((c16 + 4 * (r & 1)) ^ ((r >> 1) & 7)) << 4);
    }
  }

  f32x16 acc[2][2], mst[2][2];
#pragma unroll
  for (int i = 0; i < 2; ++i)
#pragma unroll
    for (int j = 0; j < 2; ++j) {
#pragma unroll
      for (int e = 0; e < 16; ++e) { acc[i][j][e] = 0.f; mst[i][j][e] = 0.f; }
    }

  int scE8M0 = 127;  // 2^0 = 1.0

  const int ST = K / 128;  // 8 stage-tiles
  STAGE(0, 0);
  STAGE(1, 1);

  for (int st = 0; st < ST; ++st) {
    if (st < ST - 1) { VMCNT(3); } else { VMCNT(0); }
    __builtin_amdgcn_s_barrier();
    if (st + 2 < ST) STAGE((st + 2) % 3, st + 2);

    const char* sp = smem + (st % 3) * STB;
#pragma unroll
    for (int s = 0; s < 2; ++s) {
      i32x8 av[2], bv[2];
#pragma unroll
      for (int i = 0; i < 2; ++i) {
        i32x4 t = *(const i32x4*)(sp + aAddr[i][s]);
        av[i] = (i32x8){t[0], t[1], t[2], t[3], 0, 0, 0, 0};
      }
#pragma unroll
      for (int j = 0; j < 2; ++j) {
        i32x4 t = *(const i32x4*)(sp + bAddr[j][s]);
        bv[j] = (i32x8){t[0], t[1], t[2], t[3], 0, 0, 0, 0};
      }
      __builtin_amdgcn_s_setprio(1);
#pragma unroll
      for (int i = 0; i < 2; ++i)
#pragma unroll
        for (int j = 0; j < 2; ++j)
          acc[i][j] = __builtin_amdgcn_mfma_scale_f32_32x32x64_f8f6f4(
              av[i], bv[j], acc[i][j], 4, 4, 0, scE8M0, 0, scE8M0);
      __builtin_amdgcn_s_setprio(0);
    }

    if (st & 1) {  // fold group g = st>>1: master += acc * sa[row] * sb[col]
      const int g = st >> 1;
#pragma unroll
      for (int j = 0; j < 2; ++j) {
        const float sbv = sb_lds[g * 128 + wcol * 64 + j * 32 + l31];
#pragma unroll
        for (int i = 0; i < 2; ++i) {
#pragma unroll
          for (int q = 0; q < 4; ++q) {
            f32x4 sav = *(const f32x4*)(sa_lds + g * 256 + wrow * 64 + i * 32 +
                                        q * 8 + hi2 * 4);
#pragma unroll
            for (int r = 0; r < 4; ++r)
              mst[i][j][q * 4 + r] += acc[i][j][q * 4 + r] * sav[r] * sbv;
          }
        }
      }
#pragma unroll
      for (int i = 0; i < 2; ++i)
#pragma unroll
        for (int j = 0; j < 2; ++j)
#pragma unroll
          for (int e = 0; e < 16; ++e) acc[i][j][e] = 0.f;
    }
  }
#undef STAGE

  // ---- NEW epilogue: LDS-staged coalesced C write (2 passes x 128 rows) ----
  // LDS image per pass: row rl (0..127) x 128 floats; 16B chunk c stored at
  // physical chunk c ^ (rl & 7)  (bank-free both sides, 2 lanes/bank-group).
  float* eb = (float*)smem;          // reuse ring region (64 KB <= 73728)
  const int rr2 = tid >> 5;          // 0..15 (readback row group)
  const int cc = tid & 31;           // readback 16B chunk
#pragma unroll
  for (int p = 0; p < 2; ++p) {
    __syncthreads();                 // ring reads / prev pass done
    if ((wrow >> 1) == p) {
      const int rl0 = (wrow & 1) * 64;
#pragma unroll
      for (int j = 0; j < 2; ++j) {
        const int cf0 = wcol * 64 + j * 32 + l31;       // block-local col
        const float bv = bias[n0 + cf0];
#pragma unroll
        for (int i = 0; i < 2; ++i) {
#pragma unroll
          for (int q = 0; q < 4; ++q) {
#pragma unroll
            for (int r = 0; r < 4; ++r) {
              const int rl = rl0 + i * 32 + hi2 * 4 + q * 8 + r;
              const int cp = (cf0 >> 2) ^ (rl & 7);
              eb[rl * 128 + cp * 4 + (cf0 & 3)] = mst[i][j][q * 4 + r] + bv;
            }
          }
        }
      }
    }
    __syncthreads();
    // store: instruction k writes rows {rr2, rr2+32(lanes>=32)} x 512B contiguous
#pragma unroll
    for (int k = 0; k < 8; ++k) {
      const int rl = rr2 + k * 16;
      const int cp = cc ^ (rl & 7);
      f32x4 vv = *(const f32x4*)(eb + rl * 128 + cp * 4);
      *(f32x4*)(C + (size_t)(m0 + p * 128 + rl) * N + n0 + cc * 4) = vv;
    }
  }
}

extern "C" void kernel_launch(void* const* d_in, const int* in_sizes, int n_in,
                              void* d_out, int out_size, void* d_ws, size_t ws_size,
                              hipStream_t stream) {
  const float* x = (const float*)d_in[0];     // [M,K]
  const float* w = (const float*)d_in[1];     // [N,K]
  const float* bias = (const float*)d_in[2];  // [N]
  float* out = (float*)d_out;

  const int MK = in_sizes[0];
  const int NK = in_sizes[1];
  const int N = in_sizes[2];
  const int K = NK / N;
  const int M = MK / K;

  unsigned char* qx4 = (unsigned char*)d_ws;            // M*K/2 bytes
  unsigned char* qw4 = qx4 + (size_t)MK / 2;            // N*K/2 bytes
  float* sax = (float*)(qw4 + (size_t)NK / 2);          // MK/256 f32
  float* sbx = sax + (size_t)(MK / 256);                // NK/256 f32

  const int gx = MK / 256;
  const int gtot = gx + NK / 256;
  qdq_fp4<<<(gtot + 3) / 4, 256, 0, stream>>>(x, (unsigned short*)qx4, sax, gx,
                                              w, (unsigned short*)qw4, sbx, gtot);

  hipFuncSetAttribute((const void*)gemm_fp4, hipFuncAttributeMaxDynamicSharedMemorySize,
                      LDS_TOTAL);
  dim3 grid((M / BM) * (N / BN));
  gemm_fp4<<<grid, dim3(THREADS), LDS_TOTAL, stream>>>(qx4, qw4, sax, sbx, bias, out,
                                                       M, N, K);
}

// Round 12
// 83.479 us; speedup vs baseline: 1.1279x; 1.1279x over previous
//
#include <hip/hip_runtime.h>
#include <hip/hip_bf16.h>

typedef __attribute__((ext_vector_type(4))) int i32x4;
typedef __attribute__((ext_vector_type(8))) int i32x8;
typedef __attribute__((ext_vector_type(4))) float f32x4;
typedef __attribute__((ext_vector_type(16))) float f32x16;

#define BM 128
#define BN 64
#define THREADS 256
#define STB 12288          // stage-tile: A 128r x 64B (8KB) + B 64r x 64B (4KB)
#define SA_OFF 36864       // f32 sa[4][128]
#define SB_OFF 38912       // f32 sb[4][64]
#define LDS_TOTAL 39936    // x4 blocks = 159744 <= 163840

#define VMCNT(n) asm volatile("s_waitcnt vmcnt(" #n ")" ::: "memory")

static __device__ inline void gload_lds16(const void* g, void* l) {
  __builtin_amdgcn_global_load_lds((__attribute__((address_space(1))) void*)g,
                                   (__attribute__((address_space(3))) void*)l,
                                   16, 0, 0);
}

// ---------------- QDQ -> packed E2M1 fp4 (q in {0,+-0.5,+-1}) + f32 scales ----------
// verbatim r10 (verified absmax 0.0156)
__global__ __launch_bounds__(256) void qdq_fp4(const float* __restrict__ x,
                                               unsigned short* __restrict__ qx,
                                               float* __restrict__ sax, int gx,
                                               const float* __restrict__ w,
                                               unsigned short* __restrict__ qw,
                                               float* __restrict__ sbx, int gtot) {
  int g = (blockIdx.x << 2) + (threadIdx.x >> 6);
  if (g >= gtot) return;
  const int lane = threadIdx.x & 63;
  const bool isx = (g < gx);
  const int gl = isx ? g : g - gx;
  const float* src = isx ? x : w;
  unsigned short* dst = isx ? qx : qw;
  float* sc = isx ? sax : sbx;

  const size_t base = (size_t)gl * 256 + (size_t)lane * 4;
  float4 v = *reinterpret_cast<const float4*>(src + base);
  float amax = fmaxf(fmaxf(fabsf(v.x), fabsf(v.y)), fmaxf(fabsf(v.z), fabsf(v.w)));
#pragma unroll
  for (int off = 32; off > 0; off >>= 1)
    amax = fmaxf(amax, __shfl_xor(amax, off, 64));
  const float scale = fmaxf(amax, 1e-6f);
  float in[4] = {v.x, v.y, v.z, v.w};
  unsigned enc = 0;
#pragma unroll
  for (int i = 0; i < 4; ++i) {
    float t = fabsf(in[i] / scale);
    unsigned q = t < 0.25f ? 0u : (t < 0.75f ? 1u : 2u);   // E2M1: 0 / 0.5 / 1.0
    if (in[i] < 0.0f) q |= 8u;
    enc |= q << (4 * i);
  }
  dst[(size_t)gl * 64 + lane] = (unsigned short)enc;
  if (lane == 0) sc[gl] = scale;
}

// ---------------- GEMM fp4: 4 waves x (64x32), 4 blocks/CU, 3-slot ring --------------
// 4 independent barrier domains per CU (latency decorrelation). K-loop math and
// swizzle identical to r10 (verified). acc/mst = 64 VGPR -> launch_bounds(256,4).
__global__ __launch_bounds__(THREADS, 4) void gemm_fp4(
    const unsigned char* __restrict__ A4,  // [M][K/2]
    const unsigned char* __restrict__ B4,  // [N][K/2]
    const float* __restrict__ sax,         // [M*4]
    const float* __restrict__ sbx,         // [N*4]
    const float* __restrict__ bias,        // [N]
    float* __restrict__ C,                 // [M,N]
    int M, int N, int K) {
  extern __shared__ char smem[];

  const int tid = threadIdx.x;
  const int lane = tid & 63;
  const int wid = tid >> 6;      // 0..3
  const int wm = wid >> 1;       // 0..1 -> 64-row strip
  const int wn = wid & 1;        // 0..1 -> 32-col strip
  const int l31 = lane & 31;
  const int hi2 = lane >> 5;     // k-half within 64

  const int nwg = gridDim.x;
  int bid = blockIdx.x;
  if ((nwg & 7) == 0) bid = (bid & 7) * (nwg >> 3) + (bid >> 3);
  const int ntn = N / BN;
  const int tm = bid / ntn, tn = bid % ntn;
  const int m0 = tm * BM, n0 = tn * BN;

  // scales
  float* sa_lds = (float*)(smem + SA_OFF);
  float* sb_lds = (float*)(smem + SB_OFF);
#pragma unroll
  for (int p = 0; p < 2; ++p) {
    int idx = p * 256 + tid, row = idx & 127, gg = idx >> 7;
    sa_lds[gg * 128 + row] = sax[(size_t)(m0 + row) * 4 + gg];
  }
  { int row = tid & 63, gg = tid >> 6;
    sb_lds[gg * 64 + row] = sbx[(size_t)(n0 + row) * 4 + gg]; }
  __syncthreads();

  // staging source map (inverse pair-line swizzle; measured 0-conflict since r3)
  const int u = (tid & 7) ^ ((tid >> 3) & 7);
  const int rr = 2 * (tid >> 3) + (u >> 2);   // 0..63
  const int cBy = (u & 3) * 16;
  const int Kb = K >> 1;                       // fp4 bytes per row
  const size_t srcA = (size_t)(m0 + rr) * Kb + cBy;
  const size_t srcB = (size_t)(n0 + rr) * Kb + cBy;
  const size_t aRowStep = (size_t)64 * Kb;
  const int d16 = tid * 16;

#define STAGE(slot, st) do {                                          \
    char* bb = smem + (slot) * STB;                                   \
    const unsigned char* ga = A4 + srcA + (size_t)(st) * 64;          \
    gload_lds16(ga,            bb + d16);                             \
    gload_lds16(ga + aRowStep, bb + 4096 + d16);                      \
    gload_lds16(B4 + srcB + (size_t)(st) * 64, bb + 8192 + d16);      \
  } while (0)

  // fragment read addresses: A frag i (rows wm*64+i*32), B (cols wn*32), k-step s
  int aAddr[2][2], bAddr[2];
#pragma unroll
  for (int i = 0; i < 2; ++i) {
    const int r = wm * 64 + i * 32 + l31;
#pragma unroll
    for (int s = 0; s < 2; ++s) {
      const int c16 = s * 2 + hi2;
      aAddr[i][s] = (r >> 1) * 128 + (((c16 + 4 * (r & 1)) ^ ((r >> 1) & 7)) << 4);
    }
  }
  {
    const int r = wn * 32 + l31;
#pragma unroll
    for (int s = 0; s < 2; ++s) {
      const int c16 = s * 2 + hi2;
      bAddr[s] = 8192 + (r >> 1) * 128 + (((c16 + 4 * (r & 1)) ^ ((r >> 1) & 7)) << 4);
    }
  }

  f32x16 acc[2], mst[2];
#pragma unroll
  for (int i = 0; i < 2; ++i)
#pragma unroll
    for (int e = 0; e < 16; ++e) { acc[i][e] = 0.f; mst[i][e] = 0.f; }

  int scE8M0 = 127;  // 2^0 = 1.0

  const int ST = K / 128;  // 8 stage-tiles
  STAGE(0, 0);
  STAGE(1, 1);

  for (int st = 0; st < ST; ++st) {
    if (st < ST - 1) { VMCNT(3); } else { VMCNT(0); }
    __builtin_amdgcn_s_barrier();
    if (st + 2 < ST) STAGE((st + 2) % 3, st + 2);

    const char* sp = smem + (st % 3) * STB;
#pragma unroll
    for (int s = 0; s < 2; ++s) {
      i32x8 av[2], bv;
#pragma unroll
      for (int i = 0; i < 2; ++i) {
        i32x4 t = *(const i32x4*)(sp + aAddr[i][s]);
        av[i] = (i32x8){t[0], t[1], t[2], t[3], 0, 0, 0, 0};
      }
      {
        i32x4 t = *(const i32x4*)(sp + bAddr[s]);
        bv = (i32x8){t[0], t[1], t[2], t[3], 0, 0, 0, 0};
      }
      __builtin_amdgcn_s_setprio(1);
#pragma unroll
      for (int i = 0; i < 2; ++i)
        acc[i] = __builtin_amdgcn_mfma_scale_f32_32x32x64_f8f6f4(
            av[i], bv, acc[i], 4, 4, 0, scE8M0, 0, scE8M0);
      __builtin_amdgcn_s_setprio(0);
    }

    if (st & 1) {  // fold group g = st>>1: master += acc * sa[row] * sb[col]
      const int g = st >> 1;
      const float sbv = sb_lds[g * 64 + wn * 32 + l31];
#pragma unroll
      for (int i = 0; i < 2; ++i) {
#pragma unroll
        for (int q = 0; q < 4; ++q) {
          f32x4 sav = *(const f32x4*)(sa_lds + g * 128 + wm * 64 + i * 32 +
                                      q * 8 + hi2 * 4);
#pragma unroll
          for (int r = 0; r < 4; ++r)
            mst[i][q * 4 + r] += acc[i][q * 4 + r] * sav[r] * sbv;
        }
#pragma unroll
        for (int e = 0; e < 16; ++e) acc[i][e] = 0.f;
      }
    }
  }
#undef STAGE

  // epilogue (r10-style direct stores): col = l31, row = (e&3) + 8*(e>>2) + 4*hi2
  const int col = n0 + wn * 32 + l31;
  const float bv = bias[col];
#pragma unroll
  for (int i = 0; i < 2; ++i) {
    const int rbase = m0 + wm * 64 + i * 32 + hi2 * 4;
#pragma unroll
    for (int q = 0; q < 4; ++q)
#pragma unroll
      for (int r = 0; r < 4; ++r)
        C[(size_t)(rbase + q * 8 + r) * N + col] = mst[i][q * 4 + r] + bv;
  }
}

extern "C" void kernel_launch(void* const* d_in, const int* in_sizes, int n_in,
                              void* d_out, int out_size, void* d_ws, size_t ws_size,
                              hipStream_t stream) {
  const float* x = (const float*)d_in[0];     // [M,K]
  const float* w = (const float*)d_in[1];     // [N,K]
  const float* bias = (const float*)d_in[2];  // [N]
  float* out = (float*)d_out;

  const int MK = in_sizes[0];
  const int NK = in_sizes[1];
  const int N = in_sizes[2];
  const int K = NK / N;
  const int M = MK / K;

  unsigned char* qx4 = (unsigned char*)d_ws;            // M*K/2 bytes
  unsigned char* qw4 = qx4 + (size_t)MK / 2;            // N*K/2 bytes
  float* sax = (float*)(qw4 + (size_t)NK / 2);          // MK/256 f32
  float* sbx = sax + (size_t)(MK / 256);                // NK/256 f32

  const int gx = MK / 256;
  const int gtot = gx + NK / 256;
  qdq_fp4<<<(gtot + 3) / 4, 256, 0, stream>>>(x, (unsigned short*)qx4, sax, gx,
                                              w, (unsigned short*)qw4, sbx, gtot);

  hipFuncSetAttribute((const void*)gemm_fp4, hipFuncAttributeMaxDynamicSharedMemorySize,
                      LDS_TOTAL);
  dim3 grid((M / BM) * (N / BN));
  gemm_fp4<<<grid, dim3(THREADS), LDS_TOTAL, stream>>>(qx4, qw4, sax, sbx, bias, out,
                                                       M, N, K);
}

// Round 13
// 77.619 us; speedup vs baseline: 1.2131x; 1.0755x over previous
//
#include <hip/hip_runtime.h>
#include <hip/hip_bf16.h>

typedef __attribute__((ext_vector_type(4))) int i32x4;
typedef __attribute__((ext_vector_type(8))) int i32x8;
typedef __attribute__((ext_vector_type(4))) float f32x4;
typedef __attribute__((ext_vector_type(16))) float f32x16;

#define BM 128
#define BN 64
#define THREADS 256
#define STB 12288          // stage-tile: A 128r x 64B (8KB) + B 64r x 64B (4KB)
#define SA_OFF 36864       // f32 sa[4][128]
#define SB_OFF 38912       // f32 sb[4][64]
#define LDS_TOTAL 39936    // x4 blocks = 159744 <= 163840

#define VMCNT(n) asm volatile("s_waitcnt vmcnt(" #n ")" ::: "memory")

static __device__ inline void gload_lds16(const void* g, void* l) {
  __builtin_amdgcn_global_load_lds((__attribute__((address_space(1))) void*)g,
                                   (__attribute__((address_space(3))) void*)l,
                                   16, 0, 0);
}

// ---------------- QDQ -> packed E2M1 fp4 (q in {0,+-0.5,+-1}) + f32 scales ----------
// verbatim r10/r12 (verified absmax 0.0156)
__global__ __launch_bounds__(256) void qdq_fp4(const float* __restrict__ x,
                                               unsigned short* __restrict__ qx,
                                               float* __restrict__ sax, int gx,
                                               const float* __restrict__ w,
                                               unsigned short* __restrict__ qw,
                                               float* __restrict__ sbx, int gtot) {
  int g = (blockIdx.x << 2) + (threadIdx.x >> 6);
  if (g >= gtot) return;
  const int lane = threadIdx.x & 63;
  const bool isx = (g < gx);
  const int gl = isx ? g : g - gx;
  const float* src = isx ? x : w;
  unsigned short* dst = isx ? qx : qw;
  float* sc = isx ? sax : sbx;

  const size_t base = (size_t)gl * 256 + (size_t)lane * 4;
  float4 v = *reinterpret_cast<const float4*>(src + base);
  float amax = fmaxf(fmaxf(fabsf(v.x), fabsf(v.y)), fmaxf(fabsf(v.z), fabsf(v.w)));
#pragma unroll
  for (int off = 32; off > 0; off >>= 1)
    amax = fmaxf(amax, __shfl_xor(amax, off, 64));
  const float scale = fmaxf(amax, 1e-6f);
  float in[4] = {v.x, v.y, v.z, v.w};
  unsigned enc = 0;
#pragma unroll
  for (int i = 0; i < 4; ++i) {
    float t = fabsf(in[i] / scale);
    unsigned q = t < 0.25f ? 0u : (t < 0.75f ? 1u : 2u);   // E2M1: 0 / 0.5 / 1.0
    if (in[i] < 0.0f) q |= 8u;
    enc |= q << (4 * i);
  }
  dst[(size_t)gl * 64 + lane] = (unsigned short)enc;
  if (lane == 0) sc[gl] = scale;
}

// ---------------- GEMM fp4: 4 waves x (64x32), 4 blocks/CU, 3-slot ring --------------
// r12 skeleton (best measured). Deltas: no setprio (m190: hurts non-phase-split GEMM),
// bias preloaded at prologue, non-temporal C stores (C never re-read; keep L2 for A).
__global__ __launch_bounds__(THREADS, 4) void gemm_fp4(
    const unsigned char* __restrict__ A4,  // [M][K/2]
    const unsigned char* __restrict__ B4,  // [N][K/2]
    const float* __restrict__ sax,         // [M*4]
    const float* __restrict__ sbx,         // [N*4]
    const float* __restrict__ bias,        // [N]
    float* __restrict__ C,                 // [M,N]
    int M, int N, int K) {
  extern __shared__ char smem[];

  const int tid = threadIdx.x;
  const int lane = tid & 63;
  const int wid = tid >> 6;      // 0..3
  const int wm = wid >> 1;       // 0..1 -> 64-row strip
  const int wn = wid & 1;        // 0..1 -> 32-col strip
  const int l31 = lane & 31;
  const int hi2 = lane >> 5;     // k-half within 64

  const int nwg = gridDim.x;
  int bid = blockIdx.x;
  if ((nwg & 7) == 0) bid = (bid & 7) * (nwg >> 3) + (bid >> 3);
  const int ntn = N / BN;
  const int tm = bid / ntn, tn = bid % ntn;
  const int m0 = tm * BM, n0 = tn * BN;

  // bias preload (overlaps the whole K-loop; epilogue has no dependent load)
  const int col = n0 + wn * 32 + l31;
  const float bv = bias[col];

  // scales
  float* sa_lds = (float*)(smem + SA_OFF);
  float* sb_lds = (float*)(smem + SB_OFF);
#pragma unroll
  for (int p = 0; p < 2; ++p) {
    int idx = p * 256 + tid, row = idx & 127, gg = idx >> 7;
    sa_lds[gg * 128 + row] = sax[(size_t)(m0 + row) * 4 + gg];
  }
  { int row = tid & 63, gg = tid >> 6;
    sb_lds[gg * 64 + row] = sbx[(size_t)(n0 + row) * 4 + gg]; }
  __syncthreads();

  // staging source map (inverse pair-line swizzle; measured 0-conflict since r3)
  const int u = (tid & 7) ^ ((tid >> 3) & 7);
  const int rr = 2 * (tid >> 3) + (u >> 2);   // 0..63
  const int cBy = (u & 3) * 16;
  const int Kb = K >> 1;                       // fp4 bytes per row
  const size_t srcA = (size_t)(m0 + rr) * Kb + cBy;
  const size_t srcB = (size_t)(n0 + rr) * Kb + cBy;
  const size_t aRowStep = (size_t)64 * Kb;
  const int d16 = tid * 16;

#define STAGE(slot, st) do {                                          \
    char* bb = smem + (slot) * STB;                                   \
    const unsigned char* ga = A4 + srcA + (size_t)(st) * 64;          \
    gload_lds16(ga,            bb + d16);                             \
    gload_lds16(ga + aRowStep, bb + 4096 + d16);                      \
    gload_lds16(B4 + srcB + (size_t)(st) * 64, bb + 8192 + d16);      \
  } while (0)

  // fragment read addresses: A frag i (rows wm*64+i*32), B (cols wn*32), k-step s
  int aAddr[2][2], bAddr[2];
#pragma unroll
  for (int i = 0; i < 2; ++i) {
    const int r = wm * 64 + i * 32 + l31;
#pragma unroll
    for (int s = 0; s < 2; ++s) {
      const int c16 = s * 2 + hi2;
      aAddr[i][s] = (r >> 1) * 128 + (((c16 + 4 * (r & 1)) ^ ((r >> 1) & 7)) << 4);
    }
  }
  {
    const int r = wn * 32 + l31;
#pragma unroll
    for (int s = 0; s < 2; ++s) {
      const int c16 = s * 2 + hi2;
      bAddr[s] = 8192 + (r >> 1) * 128 + (((c16 + 4 * (r & 1)) ^ ((r >> 1) & 7)) << 4);
    }
  }

  f32x16 acc[2], mst[2];
#pragma unroll
  for (int i = 0; i < 2; ++i)
#pragma unroll
    for (int e = 0; e < 16; ++e) { acc[i][e] = 0.f; mst[i][e] = 0.f; }

  int scE8M0 = 127;  // 2^0 = 1.0

  const int ST = K / 128;  // 8 stage-tiles
  STAGE(0, 0);
  STAGE(1, 1);

  for (int st = 0; st < ST; ++st) {
    if (st < ST - 1) { VMCNT(3); } else { VMCNT(0); }
    __builtin_amdgcn_s_barrier();
    if (st + 2 < ST) STAGE((st + 2) % 3, st + 2);

    const char* sp = smem + (st % 3) * STB;
#pragma unroll
    for (int s = 0; s < 2; ++s) {
      i32x8 av[2], bvv;
#pragma unroll
      for (int i = 0; i < 2; ++i) {
        i32x4 t = *(const i32x4*)(sp + aAddr[i][s]);
        av[i] = (i32x8){t[0], t[1], t[2], t[3], 0, 0, 0, 0};
      }
      {
        i32x4 t = *(const i32x4*)(sp + bAddr[s]);
        bvv = (i32x8){t[0], t[1], t[2], t[3], 0, 0, 0, 0};
      }
#pragma unroll
      for (int i = 0; i < 2; ++i)
        acc[i] = __builtin_amdgcn_mfma_scale_f32_32x32x64_f8f6f4(
            av[i], bvv, acc[i], 4, 4, 0, scE8M0, 0, scE8M0);
    }

    if (st & 1) {  // fold group g = st>>1: master += acc * sa[row] * sb[col]
      const int g = st >> 1;
      const float sbv = sb_lds[g * 64 + wn * 32 + l31];
#pragma unroll
      for (int i = 0; i < 2; ++i) {
#pragma unroll
        for (int q = 0; q < 4; ++q) {
          f32x4 sav = *(const f32x4*)(sa_lds + g * 128 + wm * 64 + i * 32 +
                                      q * 8 + hi2 * 4);
#pragma unroll
          for (int r = 0; r < 4; ++r)
            mst[i][q * 4 + r] += acc[i][q * 4 + r] * sav[r] * sbv;
        }
#pragma unroll
        for (int e = 0; e < 16; ++e) acc[i][e] = 0.f;
      }
    }
  }
#undef STAGE

  // epilogue: non-temporal stores (C never re-read); row = (e&3)+8*(e>>2)+4*hi2
#pragma unroll
  for (int i = 0; i < 2; ++i) {
    const int rbase = m0 + wm * 64 + i * 32 + hi2 * 4;
#pragma unroll
    for (int q = 0; q < 4; ++q)
#pragma unroll
      for (int r = 0; r < 4; ++r)
        __builtin_nontemporal_store(mst[i][q * 4 + r] + bv,
                                    C + (size_t)(rbase + q * 8 + r) * N + col);
  }
}

extern "C" void kernel_launch(void* const* d_in, const int* in_sizes, int n_in,
                              void* d_out, int out_size, void* d_ws, size_t ws_size,
                              hipStream_t stream) {
  const float* x = (const float*)d_in[0];     // [M,K]
  const float* w = (const float*)d_in[1];     // [N,K]
  const float* bias = (const float*)d_in[2];  // [N]
  float* out = (float*)d_out;

  const int MK = in_sizes[0];
  const int NK = in_sizes[1];
  const int N = in_sizes[2];
  const int K = NK / N;
  const int M = MK / K;

  unsigned char* qx4 = (unsigned char*)d_ws;            // M*K/2 bytes
  unsigned char* qw4 = qx4 + (size_t)MK / 2;            // N*K/2 bytes
  float* sax = (float*)(qw4 + (size_t)NK / 2);          // MK/256 f32
  float* sbx = sax + (size_t)(MK / 256);                // NK/256 f32

  const int gx = MK / 256;
  const int gtot = gx + NK / 256;
  qdq_fp4<<<(gtot + 3) / 4, 256, 0, stream>>>(x, (unsigned short*)qx4, sax, gx,
                                              w, (unsigned short*)qw4, sbx, gtot);

  hipFuncSetAttribute((const void*)gemm_fp4, hipFuncAttributeMaxDynamicSharedMemorySize,
                      LDS_TOTAL);
  dim3 grid((M / BM) * (N / BN));
  gemm_fp4<<<grid, dim3(THREADS), LDS_TOTAL, stream>>>(qx4, qw4, sax, sbx, bias, out,
                                                       M, N, K);
}

// Round 15
// 75.489 us; speedup vs baseline: 1.2473x; 1.0282x over previous
//
#include <hip/hip_runtime.h>
#include <hip/hip_bf16.h>

typedef __attribute__((ext_vector_type(4))) int i32x4;
typedef __attribute__((ext_vector_type(8))) int i32x8;
typedef __attribute__((ext_vector_type(4))) float f32x4;
typedef __attribute__((ext_vector_type(16))) float f32x16;

#define THREADS 512
#define SLOT 16384         // stage-tile: A 128r x 64B (8KB) + B 128r x 64B (8KB)
#define SA_OFF 49152       // f32 sa[4][128]
#define SB_OFF 51200       // f32 sb[4][128]
#define LDS_TOTAL 53248    // 52KB; launch_bounds(512,4) -> 2 blocks/CU

#define VMCNT(n) asm volatile("s_waitcnt vmcnt(" #n ")" ::: "memory")

static __device__ inline void gload_lds16(const void* g, void* l) {
  __builtin_amdgcn_global_load_lds((__attribute__((address_space(1))) void*)g,
                                   (__attribute__((address_space(3))) void*)l,
                                   16, 0, 0);
}

// ---------------- QDQ -> packed E2M1 fp4 (q in {0,+-0.5,+-1}) + f32 scales ----------
// verbatim r10-r13 (verified absmax 0.0156)
__global__ __launch_bounds__(256) void qdq_fp4(const float* __restrict__ x,
                                               unsigned short* __restrict__ qx,
                                               float* __restrict__ sax, int gx,
                                               const float* __restrict__ w,
                                               unsigned short* __restrict__ qw,
                                               float* __restrict__ sbx, int gtot) {
  int g = (blockIdx.x << 2) + (threadIdx.x >> 6);
  if (g >= gtot) return;
  const int lane = threadIdx.x & 63;
  const bool isx = (g < gx);
  const int gl = isx ? g : g - gx;
  const float* src = isx ? x : w;
  unsigned short* dst = isx ? qx : qw;
  float* sc = isx ? sax : sbx;

  const size_t base = (size_t)gl * 256 + (size_t)lane * 4;
  float4 v = *reinterpret_cast<const float4*>(src + base);
  float amax = fmaxf(fmaxf(fabsf(v.x), fabsf(v.y)), fmaxf(fabsf(v.z), fabsf(v.w)));
#pragma unroll
  for (int off = 32; off > 0; off >>= 1)
    amax = fmaxf(amax, __shfl_xor(amax, off, 64));
  const float scale = fmaxf(amax, 1e-6f);
  float in[4] = {v.x, v.y, v.z, v.w};
  unsigned enc = 0;
#pragma unroll
  for (int i = 0; i < 4; ++i) {
    float t = fabsf(in[i] / scale);
    unsigned q = t < 0.25f ? 0u : (t < 0.75f ? 1u : 2u);   // E2M1: 0 / 0.5 / 1.0
    if (in[i] < 0.0f) q |= 8u;
    enc |= q << (4 * i);
  }
  dst[(size_t)gl * 64 + lane] = (unsigned short)enc;
  if (lane == 0) sc[gl] = scale;
}

// ---------------- GEMM fp4: 128x128 tile, 8 waves x (64x32), 3-slot ring -------------
// r13 discipline verbatim; only the tile is widened so each staged A feeds 2x cols.
// Stage = 2 gloads (A 8KB, B 8KB; 512 thr x 16B each). Ledger: prefetch distance 2,
// outstanding before gate = STAGE(st+1) = 2 ops -> VMCNT(2) proves STAGE(st) landed;
// tail VMCNT(0). STAGE(st+2) post-barrier overwrites slot of st-1 (reads done pre-bar).
// Pair-line swizzle (measured 0-conflict since r3): byte(r,c16) = (r>>1)*128 +
//   ((c16 + 4*(r&1)) ^ ((r>>1)&7))*16 ; staging source inverse-permuted.
__global__ __launch_bounds__(THREADS, 4) void gemm_fp4(
    const unsigned char* __restrict__ A4,  // [M][K/2]
    const unsigned char* __restrict__ B4,  // [N][K/2]
    const float* __restrict__ sax,         // [M*4]
    const float* __restrict__ sbx,         // [N*4]
    const float* __restrict__ bias,        // [N]
    float* __restrict__ C,                 // [M,N]
    int M, int N, int K) {
  extern __shared__ char smem[];

  const int tid = threadIdx.x;
  const int lane = tid & 63;
  const int wid = tid >> 6;      // 0..7
  const int wm = wid >> 2;       // 0..1 -> 64-row strip
  const int wn = wid & 3;        // 0..3 -> 32-col strip
  const int l31 = lane & 31;
  const int hi2 = lane >> 5;     // k-half within 64

  const int nwg = gridDim.x;
  int bid = blockIdx.x;
  if ((nwg & 7) == 0) bid = (bid & 7) * (nwg >> 3) + (bid >> 3);
  const int ntn = N / 128;
  const int tm = bid / ntn, tn = bid % ntn;
  const int m0 = tm * 128, n0 = tn * 128;

  // bias preload (r13-verified lever)
  const int col = n0 + wn * 32 + l31;
  const float bv = bias[col];

  // scales: 512 threads cover 4 groups x 128 rows in one pass each
  float* sa_lds = (float*)(smem + SA_OFF);
  float* sb_lds = (float*)(smem + SB_OFF);
  {
    const int row = tid & 127, gg = tid >> 7;
    sa_lds[gg * 128 + row] = sax[(size_t)(m0 + row) * 4 + gg];
    sb_lds[gg * 128 + row] = sbx[(size_t)(n0 + row) * 4 + gg];
  }
  __syncthreads();

  // staging source map (inverse pair-line swizzle; 8KB region, 64 lines)
  const int u = (tid & 7) ^ ((tid >> 3) & 7);
  const int rr = 2 * (tid >> 3) + (u >> 2);   // 0..127
  const int cBy = (u & 3) * 16;
  const int Kb = K >> 1;                       // fp4 bytes per row
  const size_t srcA = (size_t)(m0 + rr) * Kb + cBy;
  const size_t srcB = (size_t)(n0 + rr) * Kb + cBy;
  const int d16 = tid * 16;                    // 0..8191

#define STAGE(slot, st) do {                                          \
    char* bb = smem + (slot) * SLOT;                                  \
    gload_lds16(A4 + srcA + (st) * 64, bb + d16);                     \
    gload_lds16(B4 + srcB + (st) * 64, bb + 8192 + d16);              \
  } while (0)

  // fragment read addresses: A rows wm*64+i*32+l31, B rows wn*32+l31, k-chunk s*2+hi2
  int aAddr[2][2], bAddr[2];
#pragma unroll
  for (int i = 0; i < 2; ++i) {
    const int r = wm * 64 + i * 32 + l31;
#pragma unroll
    for (int s = 0; s < 2; ++s) {
      const int c16 = s * 2 + hi2;
      aAddr[i][s] = (r >> 1) * 128 + (((c16 + 4 * (r & 1)) ^ ((r >> 1) & 7)) << 4);
    }
  }
  {
    const int r = wn * 32 + l31;
#pragma unroll
    for (int s = 0; s < 2; ++s) {
      const int c16 = s * 2 + hi2;
      bAddr[s] = 8192 + (r >> 1) * 128 + (((c16 + 4 * (r & 1)) ^ ((r >> 1) & 7)) << 4);
    }
  }

  f32x16 acc[2], mst[2];
#pragma unroll
  for (int i = 0; i < 2; ++i)
#pragma unroll
    for (int e = 0; e < 16; ++e) { acc[i][e] = 0.f; mst[i][e] = 0.f; }

  int scE8M0 = 127;  // E8M0 2^0 = 1.0

  const int ST = K / 128;  // 8 stage-tiles
  STAGE(0, 0);
  STAGE(1, 1);

  for (int st = 0; st < ST; ++st) {
    if (st < ST - 1) { VMCNT(2); } else { VMCNT(0); }
    __builtin_amdgcn_s_barrier();
    if (st + 2 < ST) STAGE((st + 2) % 3, st + 2);

    const char* sp = smem + (st % 3) * SLOT;
#pragma unroll
    for (int s = 0; s < 2; ++s) {
      i32x8 av[2], bvx;
#pragma unroll
      for (int i = 0; i < 2; ++i) {
        i32x4 t = *(const i32x4*)(sp + aAddr[i][s]);
        av[i] = (i32x8){t[0], t[1], t[2], t[3], 0, 0, 0, 0};
      }
      {
        i32x4 t = *(const i32x4*)(sp + bAddr[s]);
        bvx = (i32x8){t[0], t[1], t[2], t[3], 0, 0, 0, 0};
      }
#pragma unroll
      for (int i = 0; i < 2; ++i)
        acc[i] = __builtin_amdgcn_mfma_scale_f32_32x32x64_f8f6f4(
            av[i], bvx, acc[i], 4, 4, 0, scE8M0, 0, scE8M0);
    }

    if (st & 1) {  // fold group g = st>>1: master += acc * sa[row] * sb[col]
      const int g = st >> 1;
      const float sbv = sb_lds[g * 128 + wn * 32 + l31];
#pragma unroll
      for (int i = 0; i < 2; ++i) {
#pragma unroll
        for (int q = 0; q < 4; ++q) {
          f32x4 sav = *(const f32x4*)(sa_lds + g * 128 + wm * 64 + i * 32 +
                                      q * 8 + hi2 * 4);
#pragma unroll
          for (int r = 0; r < 4; ++r)
            mst[i][q * 4 + r] += acc[i][q * 4 + r] * sav[r] * sbv;
        }
#pragma unroll
        for (int e = 0; e < 16; ++e) acc[i][e] = 0.f;
      }
    }
  }
#undef STAGE

  // epilogue: non-temporal stores; row = (e&3)+8*(e>>2)+4*hi2 (m74/m101 map)
#pragma unroll
  for (int i = 0; i < 2; ++i) {
    const int rbase = m0 + wm * 64 + i * 32 + hi2 * 4;
#pragma unroll
    for (int q = 0; q < 4; ++q)
#pragma unroll
      for (int r = 0; r < 4; ++r)
        __builtin_nontemporal_store(mst[i][q * 4 + r] + bv,
                                    C + (size_t)(rbase + q * 8 + r) * N + col);
  }
}

extern "C" void kernel_launch(void* const* d_in, const int* in_sizes, int n_in,
                              void* d_out, int out_size, void* d_ws, size_t ws_size,
                              hipStream_t stream) {
  const float* x = (const float*)d_in[0];     // [M,K]
  const float* w = (const float*)d_in[1];     // [N,K]
  const float* bias = (const float*)d_in[2];  // [N]
  float* out = (float*)d_out;

  const int MK = in_sizes[0];
  const int NK = in_sizes[1];
  const int N = in_sizes[2];
  const int K = NK / N;
  const int M = MK / K;

  unsigned char* qx4 = (unsigned char*)d_ws;            // M*K/2 bytes
  unsigned char* qw4 = qx4 + (size_t)MK / 2;            // N*K/2 bytes
  float* sax = (float*)(qw4 + (size_t)NK / 2);          // MK/256 f32
  float* sbx = sax + (size_t)(MK / 256);                // NK/256 f32

  const int gx = MK / 256;
  const int gtot = gx + NK / 256;
  qdq_fp4<<<(gtot + 3) / 4, 256, 0, stream>>>(x, (unsigned short*)qx4, sax, gx,
                                              w, (unsigned short*)qw4, sbx, gtot);

  hipFuncSetAttribute((const void*)gemm_fp4, hipFuncAttributeMaxDynamicSharedMemorySize,
                      LDS_TOTAL);
  dim3 grid((M / 128) * (N / 128));
  gemm_fp4<<<grid, dim3(THREADS), LDS_TOTAL, stream>>>(qx4, qw4, sax, sbx, bias, out,
                                                       M, N, K);
}

// Round 16
// 74.763 us; speedup vs baseline: 1.2594x; 1.0097x over previous
//
#include <hip/hip_runtime.h>
#include <hip/hip_bf16.h>

typedef __attribute__((ext_vector_type(4))) int i32x4;
typedef __attribute__((ext_vector_type(8))) int i32x8;
typedef __attribute__((ext_vector_type(4))) float f32x4;
typedef __attribute__((ext_vector_type(16))) float f32x16;

#define THREADS 512
#define SLOT 16384         // stage-tile: A 128r x 64B (8KB) + B 128r x 64B (8KB)
#define NSLOT 4
#define SA_OFF 65536       // f32 sa[4][128]
#define SB_OFF 67584       // f32 sb[4][128]
#define LDS_TOTAL 69632    // 68KB; x2 blocks = 136KB <= 160KB -> 2 blocks/CU

#define VMCNT(n) asm volatile("s_waitcnt vmcnt(" #n ")" ::: "memory")

static __device__ inline void gload_lds16(const void* g, void* l) {
  __builtin_amdgcn_global_load_lds((__attribute__((address_space(1))) void*)g,
                                   (__attribute__((address_space(3))) void*)l,
                                   16, 0, 0);
}

// ---------------- QDQ -> packed E2M1 fp4 (q in {0,+-0.5,+-1}) + f32 scales ----------
// verbatim r10-r15 (verified absmax 0.0156)
__global__ __launch_bounds__(256) void qdq_fp4(const float* __restrict__ x,
                                               unsigned short* __restrict__ qx,
                                               float* __restrict__ sax, int gx,
                                               const float* __restrict__ w,
                                               unsigned short* __restrict__ qw,
                                               float* __restrict__ sbx, int gtot) {
  int g = (blockIdx.x << 2) + (threadIdx.x >> 6);
  if (g >= gtot) return;
  const int lane = threadIdx.x & 63;
  const bool isx = (g < gx);
  const int gl = isx ? g : g - gx;
  const float* src = isx ? x : w;
  unsigned short* dst = isx ? qx : qw;
  float* sc = isx ? sax : sbx;

  const size_t base = (size_t)gl * 256 + (size_t)lane * 4;
  float4 v = *reinterpret_cast<const float4*>(src + base);
  float amax = fmaxf(fmaxf(fabsf(v.x), fabsf(v.y)), fmaxf(fabsf(v.z), fabsf(v.w)));
#pragma unroll
  for (int off = 32; off > 0; off >>= 1)
    amax = fmaxf(amax, __shfl_xor(amax, off, 64));
  const float scale = fmaxf(amax, 1e-6f);
  float in[4] = {v.x, v.y, v.z, v.w};
  unsigned enc = 0;
#pragma unroll
  for (int i = 0; i < 4; ++i) {
    float t = fabsf(in[i] / scale);
    unsigned q = t < 0.25f ? 0u : (t < 0.75f ? 1u : 2u);   // E2M1: 0 / 0.5 / 1.0
    if (in[i] < 0.0f) q |= 8u;
    enc |= q << (4 * i);
  }
  dst[(size_t)gl * 64 + lane] = (unsigned short)enc;
  if (lane == 0) sc[gl] = scale;
}

// ---------------- GEMM fp4: 128x128 tile, 8 waves x (64x32), 4-slot ring -------------
// r15 verbatim except ring depth: 4 slots, prefetch distance 3.
// Ledger: at iter-st gate, outstanding newer-than-st = stages st+1,st+2 = 4 loads ->
// VMCNT(4); tail ST-2 -> VMCNT(2), ST-1 -> VMCNT(0). STAGE(st+3) post-barrier
// overwrites slot (st+3)&3 = slot of st-1 (its reads completed pre-barrier).
// Pair-line swizzle (measured 0-conflict since r3): byte(r,c16) = (r>>1)*128 +
//   ((c16 + 4*(r&1)) ^ ((r>>1)&7))*16 ; staging source inverse-permuted.
__global__ __launch_bounds__(THREADS, 4) void gemm_fp4(
    const unsigned char* __restrict__ A4,  // [M][K/2]
    const unsigned char* __restrict__ B4,  // [N][K/2]
    const float* __restrict__ sax,         // [M*4]
    const float* __restrict__ sbx,         // [N*4]
    const float* __restrict__ bias,        // [N]
    float* __restrict__ C,                 // [M,N]
    int M, int N, int K) {
  extern __shared__ char smem[];

  const int tid = threadIdx.x;
  const int lane = tid & 63;
  const int wid = tid >> 6;      // 0..7
  const int wm = wid >> 2;       // 0..1 -> 64-row strip
  const int wn = wid & 3;        // 0..3 -> 32-col strip
  const int l31 = lane & 31;
  const int hi2 = lane >> 5;     // k-half within 64

  const int nwg = gridDim.x;
  int bid = blockIdx.x;
  if ((nwg & 7) == 0) bid = (bid & 7) * (nwg >> 3) + (bid >> 3);
  const int ntn = N / 128;
  const int tm = bid / ntn, tn = bid % ntn;
  const int m0 = tm * 128, n0 = tn * 128;

  // bias preload (r13-verified lever)
  const int col = n0 + wn * 32 + l31;
  const float bv = bias[col];

  // scales: 512 threads cover 4 groups x 128 rows in one pass each
  float* sa_lds = (float*)(smem + SA_OFF);
  float* sb_lds = (float*)(smem + SB_OFF);
  {
    const int row = tid & 127, gg = tid >> 7;
    sa_lds[gg * 128 + row] = sax[(size_t)(m0 + row) * 4 + gg];
    sb_lds[gg * 128 + row] = sbx[(size_t)(n0 + row) * 4 + gg];
  }
  __syncthreads();

  // staging source map (inverse pair-line swizzle; 8KB region, 64 lines)
  const int u = (tid & 7) ^ ((tid >> 3) & 7);
  const int rr = 2 * (tid >> 3) + (u >> 2);   // 0..127
  const int cBy = (u & 3) * 16;
  const int Kb = K >> 1;                       // fp4 bytes per row
  const size_t srcA = (size_t)(m0 + rr) * Kb + cBy;
  const size_t srcB = (size_t)(n0 + rr) * Kb + cBy;
  const int d16 = tid * 16;                    // 0..8191

#define STAGE(slot, st) do {                                          \
    char* bb = smem + (slot) * SLOT;                                  \
    gload_lds16(A4 + srcA + (st) * 64, bb + d16);                     \
    gload_lds16(B4 + srcB + (st) * 64, bb + 8192 + d16);              \
  } while (0)

  // fragment read addresses: A rows wm*64+i*32+l31, B rows wn*32+l31, k-chunk s*2+hi2
  int aAddr[2][2], bAddr[2];
#pragma unroll
  for (int i = 0; i < 2; ++i) {
    const int r = wm * 64 + i * 32 + l31;
#pragma unroll
    for (int s = 0; s < 2; ++s) {
      const int c16 = s * 2 + hi2;
      aAddr[i][s] = (r >> 1) * 128 + (((c16 + 4 * (r & 1)) ^ ((r >> 1) & 7)) << 4);
    }
  }
  {
    const int r = wn * 32 + l31;
#pragma unroll
    for (int s = 0; s < 2; ++s) {
      const int c16 = s * 2 + hi2;
      bAddr[s] = 8192 + (r >> 1) * 128 + (((c16 + 4 * (r & 1)) ^ ((r >> 1) & 7)) << 4);
    }
  }

  f32x16 acc[2], mst[2];
#pragma unroll
  for (int i = 0; i < 2; ++i)
#pragma unroll
    for (int e = 0; e < 16; ++e) { acc[i][e] = 0.f; mst[i][e] = 0.f; }

  int scE8M0 = 127;  // E8M0 2^0 = 1.0

  const int ST = K / 128;  // 8 stage-tiles
  STAGE(0, 0);
  STAGE(1, 1);
  STAGE(2, 2);

  for (int st = 0; st < ST; ++st) {
    if (st < ST - 2) { VMCNT(4); } else if (st == ST - 2) { VMCNT(2); } else { VMCNT(0); }
    __builtin_amdgcn_s_barrier();
    if (st + 3 < ST) STAGE((st + 3) & 3, st + 3);

    const char* sp = smem + (st & 3) * SLOT;
#pragma unroll
    for (int s = 0; s < 2; ++s) {
      i32x8 av[2], bvx;
#pragma unroll
      for (int i = 0; i < 2; ++i) {
        i32x4 t = *(const i32x4*)(sp + aAddr[i][s]);
        av[i] = (i32x8){t[0], t[1], t[2], t[3], 0, 0, 0, 0};
      }
      {
        i32x4 t = *(const i32x4*)(sp + bAddr[s]);
        bvx = (i32x8){t[0], t[1], t[2], t[3], 0, 0, 0, 0};
      }
#pragma unroll
      for (int i = 0; i < 2; ++i)
        acc[i] = __builtin_amdgcn_mfma_scale_f32_32x32x64_f8f6f4(
            av[i], bvx, acc[i], 4, 4, 0, scE8M0, 0, scE8M0);
    }

    if (st & 1) {  // fold group g = st>>1: master += acc * sa[row] * sb[col]
      const int g = st >> 1;
      const float sbv = sb_lds[g * 128 + wn * 32 + l31];
#pragma unroll
      for (int i = 0; i < 2; ++i) {
#pragma unroll
        for (int q = 0; q < 4; ++q) {
          f32x4 sav = *(const f32x4*)(sa_lds + g * 128 + wm * 64 + i * 32 +
                                      q * 8 + hi2 * 4);
#pragma unroll
          for (int r = 0; r < 4; ++r)
            mst[i][q * 4 + r] += acc[i][q * 4 + r] * sav[r] * sbv;
        }
#pragma unroll
        for (int e = 0; e < 16; ++e) acc[i][e] = 0.f;
      }
    }
  }
#undef STAGE

  // epilogue: non-temporal stores; row = (e&3)+8*(e>>2)+4*hi2 (m74/m101 map)
#pragma unroll
  for (int i = 0; i < 2; ++i) {
    const int rbase = m0 + wm * 64 + i * 32 + hi2 * 4;
#pragma unroll
    for (int q = 0; q < 4; ++q)
#pragma unroll
      for (int r = 0; r < 4; ++r)
        __builtin_nontemporal_store(mst[i][q * 4 + r] + bv,
                                    C + (size_t)(rbase + q * 8 + r) * N + col);
  }
}

extern "C" void kernel_launch(void* const* d_in, const int* in_sizes, int n_in,
                              void* d_out, int out_size, void* d_ws, size_t ws_size,
                              hipStream_t stream) {
  const float* x = (const float*)d_in[0];     // [M,K]
  const float* w = (const float*)d_in[1];     // [N,K]
  const float* bias = (const float*)d_in[2];  // [N]
  float* out = (float*)d_out;

  const int MK = in_sizes[0];
  const int NK = in_sizes[1];
  const int N = in_sizes[2];
  const int K = NK / N;
  const int M = MK / K;

  unsigned char* qx4 = (unsigned char*)d_ws;            // M*K/2 bytes
  unsigned char* qw4 = qx4 + (size_t)MK / 2;            // N*K/2 bytes
  float* sax = (float*)(qw4 + (size_t)NK / 2);          // MK/256 f32
  float* sbx = sax + (size_t)(MK / 256);                // NK/256 f32

  const int gx = MK / 256;
  const int gtot = gx + NK / 256;
  qdq_fp4<<<(gtot + 3) / 4, 256, 0, stream>>>(x, (unsigned short*)qx4, sax, gx,
                                              w, (unsigned short*)qw4, sbx, gtot);

  hipFuncSetAttribute((const void*)gemm_fp4, hipFuncAttributeMaxDynamicSharedMemorySize,
                      LDS_TOTAL);
  dim3 grid((M / 128) * (N / 128));
  gemm_fp4<<<grid, dim3(THREADS), LDS_TOTAL, stream>>>(qx4, qw4, sax, sbx, bias, out,
                                                       M, N, K);
}